// Round 1
// baseline (1719.920 us; speedup 1.0000x reference)
//
#include <hip/hip_runtime.h>
#include <hip/hip_bf16.h>
#include <math.h>

// ---------------- model dims ----------------
#define BB    8
#define TT    511
#define TC    512          // T+1 (cls prepended)
#define DD    512
#define HH    8
#define HD    64
#define LL    4
#define FF    256
#define HEADH 32
#define NTOK  (BB*TC)      // 4096
#define NEGV  (-1e9f)

// ---------------- wave helpers ----------------
__device__ __forceinline__ float wsum(float v) {
#pragma unroll
  for (int m = 32; m >= 1; m >>= 1) v += __shfl_xor(v, m, 64);
  return v;
}
__device__ __forceinline__ float wmaxr(float v) {
#pragma unroll
  for (int m = 32; m >= 1; m >>= 1) v = fmaxf(v, __shfl_xor(v, m, 64));
  return v;
}
__device__ __forceinline__ float gelu_f(float x) {
  return 0.5f * x * (1.0f + erff(x * 0.7071067811865476f));
}

// ---------------- embed + pad mask ----------------
// h[b][0][:] = cls;  h[b][t][:] = embed[x[b][t-1]] * (x!=0) + pos[t-1]   (t>=1)
// pad[b*512+t] = (t>0 && x[b][t-1]==0)
__global__ void embed_k(const int* __restrict__ x, const float* __restrict__ etab,
                        const float* __restrict__ ptab, const float* __restrict__ cls,
                        float* __restrict__ h, int* __restrict__ pad) {
  const int tok = blockIdx.x;             // 0..4095
  const int b = tok >> 9, t = tok & 511;
  const int lane = threadIdx.x;           // 64
  float4 o0, o1;
  int isPad = 0;
  if (t == 0) {
    o0 = ((const float4*)cls)[lane];
    o1 = ((const float4*)cls)[64 + lane];
  } else {
    const int id = x[b * TT + (t - 1)];
    isPad = (id == 0);
    const float m = isPad ? 0.0f : 1.0f;
    const float4* e  = (const float4*)(etab + (size_t)id * DD);
    const float4* pp = (const float4*)(ptab + (size_t)(t - 1) * DD);
    float4 e0 = e[lane], e1 = e[64 + lane];
    float4 p0 = pp[lane], p1 = pp[64 + lane];
    o0.x = e0.x * m + p0.x; o0.y = e0.y * m + p0.y;
    o0.z = e0.z * m + p0.z; o0.w = e0.w * m + p0.w;
    o1.x = e1.x * m + p1.x; o1.y = e1.y * m + p1.y;
    o1.z = e1.z * m + p1.z; o1.w = e1.w * m + p1.w;
  }
  float4* hp = (float4*)(h + (size_t)tok * DD);
  hp[lane] = o0; hp[64 + lane] = o1;
  if (lane == 0) pad[tok] = isPad;
}

// ---------------- layernorm (wave per row, D=512) ----------------
__global__ __launch_bounds__(256) void ln_rows(const float* __restrict__ in,
                                               float* __restrict__ out,
                                               const float* __restrict__ g,
                                               const float* __restrict__ b) {
  const int wave = threadIdx.x >> 6, lane = threadIdx.x & 63;
  const int row = blockIdx.x * 4 + wave;
  const float* p = in + (size_t)row * DD;
  float4 a = ((const float4*)p)[lane];
  float4 c = ((const float4*)p)[64 + lane];
  float v[8] = {a.x, a.y, a.z, a.w, c.x, c.y, c.z, c.w};
  float s = 0.f;
#pragma unroll
  for (int i = 0; i < 8; ++i) s += v[i];
  const float m = wsum(s) * (1.0f / 512.0f);
  float sq = 0.f;
#pragma unroll
  for (int i = 0; i < 8; ++i) { float d = v[i] - m; sq = fmaf(d, d, sq); }
  const float rs = rsqrtf(wsum(sq) * (1.0f / 512.0f) + 1e-5f);
  float4 g0 = ((const float4*)g)[lane], g1 = ((const float4*)g)[64 + lane];
  float4 b0 = ((const float4*)b)[lane], b1 = ((const float4*)b)[64 + lane];
  float4 r0, r1;
  r0.x = (v[0] - m) * rs * g0.x + b0.x; r0.y = (v[1] - m) * rs * g0.y + b0.y;
  r0.z = (v[2] - m) * rs * g0.z + b0.z; r0.w = (v[3] - m) * rs * g0.w + b0.w;
  r1.x = (v[4] - m) * rs * g1.x + b1.x; r1.y = (v[5] - m) * rs * g1.y + b1.y;
  r1.z = (v[6] - m) * rs * g1.z + b1.z; r1.w = (v[7] - m) * rs * g1.w + b1.w;
  float4* op = (float4*)(out + (size_t)row * DD);
  op[lane] = r0; op[64 + lane] = r1;
}

// h = LN(t + xin)*g + b + h   (in-place on h)
__global__ __launch_bounds__(256) void resid_ln(const float* __restrict__ t,
                                                const float* __restrict__ xin,
                                                float* __restrict__ h,
                                                const float* __restrict__ g,
                                                const float* __restrict__ b) {
  const int wave = threadIdx.x >> 6, lane = threadIdx.x & 63;
  const int row = blockIdx.x * 4 + wave;
  const float* tp = t + (size_t)row * DD;
  const float* xp = xin + (size_t)row * DD;
  float4 t0 = ((const float4*)tp)[lane], t1 = ((const float4*)tp)[64 + lane];
  float4 x0 = ((const float4*)xp)[lane], x1 = ((const float4*)xp)[64 + lane];
  float v[8] = {t0.x + x0.x, t0.y + x0.y, t0.z + x0.z, t0.w + x0.w,
                t1.x + x1.x, t1.y + x1.y, t1.z + x1.z, t1.w + x1.w};
  float s = 0.f;
#pragma unroll
  for (int i = 0; i < 8; ++i) s += v[i];
  const float m = wsum(s) * (1.0f / 512.0f);
  float sq = 0.f;
#pragma unroll
  for (int i = 0; i < 8; ++i) { float d = v[i] - m; sq = fmaf(d, d, sq); }
  const float rs = rsqrtf(wsum(sq) * (1.0f / 512.0f) + 1e-5f);
  float4 g0 = ((const float4*)g)[lane], g1 = ((const float4*)g)[64 + lane];
  float4 b0 = ((const float4*)b)[lane], b1 = ((const float4*)b)[64 + lane];
  float4* hp = (float4*)(h + (size_t)row * DD);
  float4 h0 = hp[lane], h1 = hp[64 + lane];
  h0.x += (v[0] - m) * rs * g0.x + b0.x; h0.y += (v[1] - m) * rs * g0.y + b0.y;
  h0.z += (v[2] - m) * rs * g0.z + b0.z; h0.w += (v[3] - m) * rs * g0.w + b0.w;
  h1.x += (v[4] - m) * rs * g1.x + b1.x; h1.y += (v[5] - m) * rs * g1.y + b1.y;
  h1.z += (v[6] - m) * rs * g1.z + b1.z; h1.w += (v[7] - m) * rs * g1.w + b1.w;
  hp[lane] = h0; hp[64 + lane] = h1;
}

// ---------------- generic tiled f32 GEMM: C[M,N] = A[M,K] @ W[K,N] ----------------
// act: 0 none, 1 gelu.  resAdd: C += result instead of C = result.
__global__ __launch_bounds__(256) void gemm64(const float* __restrict__ A,
                                              const float* __restrict__ W,
                                              float* __restrict__ C,
                                              int M, int N, int K,
                                              const float* __restrict__ bias,
                                              int act, int resAdd) {
  __shared__ float sA[16][68];   // [kk][m]
  __shared__ float sW[16][68];   // [kk][n]
  const int tid = threadIdx.x;
  const int tx = tid & 15, ty = tid >> 4;
  const int row0 = blockIdx.y << 6, col0 = blockIdx.x << 6;
  const int mload = tid >> 2, kload = (tid & 3) << 2;
  const int krow = tid >> 4, nload = (tid & 15) << 2;
  float acc[4][4] = {};
  for (int k0 = 0; k0 < K; k0 += 16) {
    __syncthreads();
    float4 av = *(const float4*)&A[(size_t)(row0 + mload) * K + k0 + kload];
    sA[kload + 0][mload] = av.x; sA[kload + 1][mload] = av.y;
    sA[kload + 2][mload] = av.z; sA[kload + 3][mload] = av.w;
    *(float4*)&sW[krow][nload] = *(const float4*)&W[(size_t)(k0 + krow) * N + col0 + nload];
    __syncthreads();
#pragma unroll
    for (int kk = 0; kk < 16; ++kk) {
      float a_[4], b_[4];
#pragma unroll
      for (int i = 0; i < 4; ++i) a_[i] = sA[kk][ty * 4 + i];
#pragma unroll
      for (int j = 0; j < 4; ++j) b_[j] = sW[kk][tx * 4 + j];
#pragma unroll
      for (int i = 0; i < 4; ++i)
#pragma unroll
        for (int j = 0; j < 4; ++j) acc[i][j] = fmaf(a_[i], b_[j], acc[i][j]);
    }
  }
#pragma unroll
  for (int i = 0; i < 4; ++i) {
    const int r = row0 + ty * 4 + i;
#pragma unroll
    for (int j = 0; j < 4; ++j) {
      const int c = col0 + tx * 4 + j;
      float v = acc[i][j];
      if (bias) v += bias[c];
      if (act == 1) v = gelu_f(v);
      const size_t idx = (size_t)r * N + c;
      if (resAdd) v += C[idx];
      C[idx] = v;
    }
  }
}

// ---------------- scores = (Q K^T)/8, key-pad mask -> NEG ----------------
// q,k: [B,Tc,D] with head slice cols [hh*64, hh*64+64). sc: [B*H, Tc, Tc]
__global__ __launch_bounds__(256) void qk_scores(const float* __restrict__ q,
                                                 const float* __restrict__ k,
                                                 const int* __restrict__ pad,
                                                 float* __restrict__ sc) {
  __shared__ float sQ[64][68];    // [i][kk]
  __shared__ float sKT[64][68];   // [kk][j]
  const int bh = blockIdx.z, b = bh >> 3, hh = bh & 7;
  const int i0 = blockIdx.y << 6, j0 = blockIdx.x << 6;
  const int tid = threadIdx.x, tx = tid & 15, ty = tid >> 4;
  const int r = tid >> 2, c0 = (tid & 3) << 4;
  const float* qb = q + ((size_t)(b * TC + i0)) * DD + hh * HD;
  const float* kb = k + ((size_t)(b * TC + j0)) * DD + hh * HD;
#pragma unroll
  for (int s = 0; s < 4; ++s) {
    const int c = c0 + 4 * s;
    *(float4*)&sQ[r][c] = *(const float4*)&qb[(size_t)r * DD + c];
    float4 kv = *(const float4*)&kb[(size_t)r * DD + c];
    sKT[c + 0][r] = kv.x; sKT[c + 1][r] = kv.y;
    sKT[c + 2][r] = kv.z; sKT[c + 3][r] = kv.w;
  }
  __syncthreads();
  float acc[4][4] = {};
#pragma unroll 16
  for (int kk = 0; kk < 64; ++kk) {
    float a_[4], b_[4];
#pragma unroll
    for (int i = 0; i < 4; ++i) a_[i] = sQ[ty * 4 + i][kk];
#pragma unroll
    for (int j = 0; j < 4; ++j) b_[j] = sKT[kk][tx * 4 + j];
#pragma unroll
    for (int i = 0; i < 4; ++i)
#pragma unroll
      for (int j = 0; j < 4; ++j) acc[i][j] = fmaf(a_[i], b_[j], acc[i][j]);
  }
#pragma unroll
  for (int j = 0; j < 4; ++j) {
    const int jj = j0 + tx * 4 + j;
    const int msk = pad[b * TC + jj];
#pragma unroll
    for (int i = 0; i < 4; ++i) {
      const float v = msk ? NEGV : acc[i][j] * 0.125f;
      sc[((size_t)bh * TC + i0 + ty * 4 + i) * TC + jj] = v;
    }
  }
}

// ---------------- entmax15 (wave per row of 512), bisection for tau ----------------
__global__ __launch_bounds__(256) void entmax_k(float* __restrict__ sc) {
  const int wave = threadIdx.x >> 6, lane = threadIdx.x & 63;
  const int row = blockIdx.x * 4 + wave;          // 0 .. 32767
  float* p = sc + (size_t)row * TC;
  float4 a = ((const float4*)p)[lane];
  float4 c = ((const float4*)p)[64 + lane];
  float v[8] = {a.x, a.y, a.z, a.w, c.x, c.y, c.z, c.w};
  float mx = -3.4e38f;
#pragma unroll
  for (int i = 0; i < 8; ++i) { v[i] *= 0.5f; mx = fmaxf(mx, v[i]); }
  mx = wmaxr(mx);
#pragma unroll
  for (int i = 0; i < 8; ++i) v[i] -= mx;
  // f(tau) = sum relu(v-tau)^2 is strictly decreasing; f(-1)>=1 (max elem), f(0)=0.
  float lo = -1.0f, hi = 0.0f;
  for (int it = 0; it < 40; ++it) {
    const float mid = 0.5f * (lo + hi);
    float s = 0.f;
#pragma unroll
    for (int i = 0; i < 8; ++i) { float d = fmaxf(v[i] - mid, 0.f); s = fmaf(d, d, s); }
    s = wsum(s);
    if (s >= 1.0f) lo = mid; else hi = mid;
  }
  const float tau = 0.5f * (lo + hi);
  float pv[8]; float s = 0.f;
#pragma unroll
  for (int i = 0; i < 8; ++i) { float d = fmaxf(v[i] - tau, 0.f); pv[i] = d * d; s += pv[i]; }
  s = wsum(s);
  const float inv = 1.0f / s;   // s ~ 1; renormalize to kill bisection residual
  float4 o0, o1;
  o0.x = pv[0] * inv; o0.y = pv[1] * inv; o0.z = pv[2] * inv; o0.w = pv[3] * inv;
  o1.x = pv[4] * inv; o1.y = pv[5] * inv; o1.z = pv[6] * inv; o1.w = pv[7] * inv;
  ((float4*)p)[lane] = o0; ((float4*)p)[64 + lane] = o1;
}

// ---------------- o = A @ V  (per b,h: [512x512]@[512x64]) ----------------
__global__ __launch_bounds__(256) void av_k(const float* __restrict__ A,
                                            const float* __restrict__ v,
                                            float* __restrict__ o) {
  __shared__ float sA[64][68];  // [i][kk]
  __shared__ float sV[64][68];  // [kk][d]
  const int bh = blockIdx.y, b = bh >> 3, hh = bh & 7;
  const int i0 = blockIdx.x << 6;
  const int tid = threadIdx.x, tx = tid & 15, ty = tid >> 4;
  const int r = tid >> 2, c0 = (tid & 3) << 4;
  const float* Ab = A + ((size_t)bh * TC + i0) * TC;
  const float* vb = v + (size_t)(b * TC) * DD + hh * HD;
  float acc[4][4] = {};
  for (int j0 = 0; j0 < TC; j0 += 64) {
    __syncthreads();
#pragma unroll
    for (int s = 0; s < 4; ++s) {
      const int c = c0 + 4 * s;
      *(float4*)&sA[r][c] = *(const float4*)&Ab[(size_t)r * TC + j0 + c];
      *(float4*)&sV[r][c] = *(const float4*)&vb[(size_t)(j0 + r) * DD + c];
    }
    __syncthreads();
#pragma unroll 16
    for (int kk = 0; kk < 64; ++kk) {
      float a_[4], b_[4];
#pragma unroll
      for (int i = 0; i < 4; ++i) a_[i] = sA[ty * 4 + i][kk];
#pragma unroll
      for (int j = 0; j < 4; ++j) b_[j] = sV[kk][tx * 4 + j];
#pragma unroll
      for (int i = 0; i < 4; ++i)
#pragma unroll
        for (int j = 0; j < 4; ++j) acc[i][j] = fmaf(a_[i], b_[j], acc[i][j]);
    }
  }
#pragma unroll
  for (int i = 0; i < 4; ++i)
#pragma unroll
    for (int j = 0; j < 4; ++j)
      o[((size_t)(b * TC + i0 + ty * 4 + i)) * DD + hh * HD + tx * 4 + j] = acc[i][j];
}

// ---------------- head: out[b] = relu(h[b,0,:]@W1+b1) @ W2 + b2 ----------------
__global__ void head_k(const float* __restrict__ h, const float* __restrict__ w1,
                       const float* __restrict__ b1, const float* __restrict__ w2,
                       const float* __restrict__ b2, float* __restrict__ out) {
  __shared__ float z[BB][HEADH];
  const int tid = threadIdx.x;            // 256 = 8*32
  const int b = tid >> 5, j = tid & 31;
  const float* hr = h + (size_t)(b * TC) * DD;
  float s = 0.f;
  for (int kk = 0; kk < DD; ++kk) s = fmaf(hr[kk], w1[kk * HEADH + j], s);
  z[b][j] = fmaxf(s + b1[j], 0.f);
  __syncthreads();
  if (tid < BB) {
    float acc = b2[0];
#pragma unroll
    for (int q = 0; q < HEADH; ++q) acc = fmaf(z[tid][q], w2[q], acc);
    out[tid] = acc;
  }
}

// ---------------- workspace fallback (if ws_size too small) ----------------
// need: 6 * 4096*512 f32 + 64 MiB scores + 4096 ints = 117,456,896 bytes
#define WS_NEED 117456896ull
static __device__ __align__(256) unsigned char g_fallback_ws[WS_NEED];

extern "C" void kernel_launch(void* const* d_in, const int* in_sizes, int n_in,
                              void* d_out, int out_size, void* d_ws, size_t ws_size,
                              hipStream_t stream) {
  const int*   x     = (const int*)d_in[0];
  const float* etab  = (const float*)d_in[1];
  const float* ptab  = (const float*)d_in[2];
  const float* cls   = (const float*)d_in[3];
  const float* Wq    = (const float*)d_in[4];
  const float* Wk    = (const float*)d_in[5];
  const float* Wv    = (const float*)d_in[6];
  const float* Wo    = (const float*)d_in[7];
  const float* an_g  = (const float*)d_in[8];
  const float* an_b  = (const float*)d_in[9];
  const float* ln1_g = (const float*)d_in[10];
  const float* ln1_b = (const float*)d_in[11];
  const float* ln2_g = (const float*)d_in[12];
  const float* ln2_b = (const float*)d_in[13];
  const float* f1_w  = (const float*)d_in[14];
  const float* f1_b  = (const float*)d_in[15];
  const float* f2_w  = (const float*)d_in[16];
  const float* f2_b  = (const float*)d_in[17];
  const float* h1_w  = (const float*)d_in[18];
  const float* h1_b  = (const float*)d_in[19];
  const float* h2_w  = (const float*)d_in[20];
  const float* h2_b  = (const float*)d_in[21];
  float* out = (float*)d_out;

  void* wsbase = d_ws;
  if (ws_size < WS_NEED) {
    hipGetSymbolAddress(&wsbase, HIP_SYMBOL(g_fallback_ws));  // host-side query, capture-safe
  }
  float* h_   = (float*)wsbase;                 // [4096][512]
  float* xin_ = h_ + (size_t)NTOK * DD;         // [4096][512]
  float* q_   = xin_ + (size_t)NTOK * DD;       // [4096][512]  (also tmp after attn)
  float* k_   = q_ + (size_t)NTOK * DD;         // [4096][512]  (also attnout)
  float* v_   = k_ + (size_t)NTOK * DD;         // [4096][512]  (also ffnmid)
  float* sc_  = v_ + (size_t)NTOK * DD;         // [64][512][512]
  int*   pad_ = (int*)(sc_ + (size_t)64 * TC * TC);  // [4096]

  embed_k<<<NTOK, 64, 0, stream>>>(x, etab, ptab, cls, h_, pad_);

  for (int l = 0; l < LL; ++l) {
    const float* Wq_l = Wq + (size_t)l * DD * DD;
    const float* Wk_l = Wk + (size_t)l * DD * DD;
    const float* Wv_l = Wv + (size_t)l * DD * DD;
    const float* Wo_l = Wo + (size_t)l * DD * DD;

    ln_rows<<<NTOK / 4, 256, 0, stream>>>(h_, xin_, ln1_g + l * DD, ln1_b + l * DD);

    gemm64<<<dim3(DD / 64, NTOK / 64), 256, 0, stream>>>(xin_, Wq_l, q_, NTOK, DD, DD, nullptr, 0, 0);
    gemm64<<<dim3(DD / 64, NTOK / 64), 256, 0, stream>>>(xin_, Wk_l, k_, NTOK, DD, DD, nullptr, 0, 0);
    gemm64<<<dim3(DD / 64, NTOK / 64), 256, 0, stream>>>(xin_, Wv_l, v_, NTOK, DD, DD, nullptr, 0, 0);

    qk_scores<<<dim3(TC / 64, TC / 64, BB * HH), 256, 0, stream>>>(q_, k_, pad_, sc_);
    entmax_k<<<(BB * HH * TC) / 4, 256, 0, stream>>>(sc_);
    av_k<<<dim3(TC / 64, BB * HH), 256, 0, stream>>>(sc_, v_, k_ /*attnout*/);

    gemm64<<<dim3(DD / 64, NTOK / 64), 256, 0, stream>>>(k_, Wo_l, q_ /*tmp*/, NTOK, DD, DD, nullptr, 0, 0);
    resid_ln<<<NTOK / 4, 256, 0, stream>>>(q_, xin_, h_, an_g + l * DD, an_b + l * DD);

    ln_rows<<<NTOK / 4, 256, 0, stream>>>(h_, xin_, ln2_g + l * DD, ln2_b + l * DD);
    gemm64<<<dim3(FF / 64, NTOK / 64), 256, 0, stream>>>(xin_, f1_w + (size_t)l * DD * FF,
                                                         v_ /*ffnmid*/, NTOK, FF, DD,
                                                         f1_b + l * FF, 1 /*gelu*/, 0);
    gemm64<<<dim3(DD / 64, NTOK / 64), 256, 0, stream>>>(v_, f2_w + (size_t)l * FF * DD,
                                                         h_, NTOK, DD, FF,
                                                         f2_b + l * DD, 0, 1 /*resAdd*/);
  }

  head_k<<<1, 256, 0, stream>>>(h_, h1_w, h1_b, h2_w, h2_b, out);
}

// Round 2
// 679.775 us; speedup vs baseline: 2.5301x; 2.5301x over previous
//
#include <hip/hip_runtime.h>
#include <hip/hip_bf16.h>
#include <math.h>

// ---------------- model dims ----------------
#define BB    8
#define TT    511
#define TC    512
#define DD    512
#define HH    8
#define HD    64
#define LL    4
#define FF    256
#define HEADH 32
#define NTOK  (BB*TC)      // 4096
#define NEGV  (-1e9f)

typedef __bf16 bf16x8 __attribute__((ext_vector_type(8)));
typedef float  f32x4  __attribute__((ext_vector_type(4)));

__device__ __forceinline__ unsigned short f2b(float v) {
  __bf16 t = (__bf16)v;
  return __builtin_bit_cast(unsigned short, t);
}
__device__ __forceinline__ float gelu_f(float x) {
  return 0.5f * x * (1.0f + erff(x * 0.7071067811865476f));
}

// ---------------- fast wave reduce: DPP xor1,2,7,15 + ds_swizzle xor16 + readlane pair ----
template<int CTRL>
__device__ __forceinline__ float dppmov(float x) {
  return __builtin_bit_cast(float,
      __builtin_amdgcn_update_dpp(0, __builtin_bit_cast(int, x), CTRL, 0xF, 0xF, true));
}
__device__ __forceinline__ float wsum(float v) {
  v += dppmov<0xB1>(v);    // xor1 (quad_perm 1,0,3,2)
  v += dppmov<0x4E>(v);    // xor2 (quad_perm 2,3,0,1)
  v += dppmov<0x141>(v);   // xor7 (row_half_mirror)
  v += dppmov<0x140>(v);   // xor15 (row_mirror)
  v += __builtin_bit_cast(float, __builtin_amdgcn_ds_swizzle(__builtin_bit_cast(int, v), 0x401F)); // xor16
  float a = __builtin_bit_cast(float, __builtin_amdgcn_readlane(__builtin_bit_cast(int, v), 0));
  float b = __builtin_bit_cast(float, __builtin_amdgcn_readlane(__builtin_bit_cast(int, v), 32));
  return a + b;
}
__device__ __forceinline__ float wmaxr(float v) {
  v = fmaxf(v, dppmov<0xB1>(v));
  v = fmaxf(v, dppmov<0x4E>(v));
  v = fmaxf(v, dppmov<0x141>(v));
  v = fmaxf(v, dppmov<0x140>(v));
  v = fmaxf(v, __builtin_bit_cast(float, __builtin_amdgcn_ds_swizzle(__builtin_bit_cast(int, v), 0x401F)));
  float a = __builtin_bit_cast(float, __builtin_amdgcn_readlane(__builtin_bit_cast(int, v), 0));
  float b = __builtin_bit_cast(float, __builtin_amdgcn_readlane(__builtin_bit_cast(int, v), 32));
  return fmaxf(a, b);
}

// ---------------- async global->LDS staging with both-sides XOR swizzle ----------------
// LDS rows of 128B (64 bf16). lds slot (row, s) <- global slot (row, s^(row&7)).
// Reader XORs the same way, so reads land conflict-free and see linear data.
__device__ __forceinline__ void stage_rows(char* lds, const char* g, size_t gstride,
                                           int nIss, int wid, int nw, int lane) {
  for (int is = wid; is < nIss; is += nw) {
    const int row = (is << 3) + (lane >> 3);
    const int s = lane & 7;
    const char* gp = g + (size_t)row * gstride + (((s ^ (row & 7))) << 4);
    __builtin_amdgcn_global_load_lds((const __attribute__((address_space(1))) void*)gp,
                                     (__attribute__((address_space(3))) void*)(lds + ((size_t)is << 10)),
                                     16, 0, 0);
  }
}
__device__ __forceinline__ bf16x8 frag_ld(const char* lds, int row, int kslot) {
  return *(const bf16x8*)(lds + row * 128 + ((kslot ^ (row & 7)) << 4));
}

// ---------------- embed + pad mask ----------------
__global__ void embed_k(const int* __restrict__ x, const float* __restrict__ etab,
                        const float* __restrict__ ptab, const float* __restrict__ cls,
                        float* __restrict__ h, int* __restrict__ pad) {
  const int tok = blockIdx.x;
  const int b = tok >> 9, t = tok & 511;
  const int lane = threadIdx.x;
  float4 o0, o1;
  int isPad = 0;
  if (t == 0) {
    o0 = ((const float4*)cls)[lane];
    o1 = ((const float4*)cls)[64 + lane];
  } else {
    const int id = x[b * TT + (t - 1)];
    isPad = (id == 0);
    const float m = isPad ? 0.0f : 1.0f;
    const float4* e  = (const float4*)(etab + (size_t)id * DD);
    const float4* pp = (const float4*)(ptab + (size_t)(t - 1) * DD);
    float4 e0 = e[lane], e1 = e[64 + lane];
    float4 p0 = pp[lane], p1 = pp[64 + lane];
    o0.x = e0.x * m + p0.x; o0.y = e0.y * m + p0.y;
    o0.z = e0.z * m + p0.z; o0.w = e0.w * m + p0.w;
    o1.x = e1.x * m + p1.x; o1.y = e1.y * m + p1.y;
    o1.z = e1.z * m + p1.z; o1.w = e1.w * m + p1.w;
  }
  float4* hp = (float4*)(h + (size_t)tok * DD);
  hp[lane] = o0; hp[64 + lane] = o1;
  if (lane == 0) pad[tok] = isPad;
}

// ---------------- weight transpose + bf16 convert (one kernel, 24 jobs) ----------------
__global__ __launch_bounds__(256) void wprep(const float* __restrict__ Wq, const float* __restrict__ Wk,
                                             const float* __restrict__ Wv, const float* __restrict__ Wo,
                                             const float* __restrict__ f1w, const float* __restrict__ f2w,
                                             unsigned short* __restrict__ qkvT, unsigned short* __restrict__ woT,
                                             unsigned short* __restrict__ f1T, unsigned short* __restrict__ f2T) {
  const int z = blockIdx.z;
  const float* src; unsigned short* dst; int K, N;
  if (z < 12) { int l = z / 3, w = z % 3;
    src = (w == 0 ? Wq : w == 1 ? Wk : Wv) + (size_t)l * 512 * 512; K = 512; N = 512;
    dst = qkvT + (size_t)l * 1536 * 512 + (size_t)w * 512 * 512;
  } else if (z < 16) { int l = z - 12; src = Wo + (size_t)l * 512 * 512; K = 512; N = 512;
    dst = woT + (size_t)l * 512 * 512;
  } else if (z < 20) { int l = z - 16; src = f1w + (size_t)l * 512 * 256; K = 512; N = 256;
    dst = f1T + (size_t)l * 256 * 512;
  } else { int l = z - 20; src = f2w + (size_t)l * 256 * 512; K = 256; N = 512;
    dst = f2T + (size_t)l * 512 * 256;
  }
  const int n0 = blockIdx.x * 32, k0 = blockIdx.y * 32;
  if (n0 >= N || k0 >= K) return;
  __shared__ float tbuf[32][33];
  const int tx = threadIdx.x & 31, ty = threadIdx.x >> 5;
#pragma unroll
  for (int i = 0; i < 32; i += 8)
    tbuf[ty + i][tx] = src[(size_t)(k0 + ty + i) * N + n0 + tx];
  __syncthreads();
#pragma unroll
  for (int i = 0; i < 32; i += 8)
    dst[(size_t)(n0 + ty + i) * K + k0 + tx] = f2b(tbuf[tx][ty + i]);
}

// ---------------- layernorm: f32 out (optional) + bf16 out ----------------
__global__ __launch_bounds__(256) void ln_rows(const float* __restrict__ in,
                                               float* __restrict__ outf,
                                               unsigned short* __restrict__ outb,
                                               const float* __restrict__ g,
                                               const float* __restrict__ b) {
  const int wave = threadIdx.x >> 6, lane = threadIdx.x & 63;
  const int row = blockIdx.x * 4 + wave;
  const float* p = in + (size_t)row * DD;
  float4 a = ((const float4*)p)[lane];
  float4 c = ((const float4*)p)[64 + lane];
  float v[8] = {a.x, a.y, a.z, a.w, c.x, c.y, c.z, c.w};
  float s = 0.f;
#pragma unroll
  for (int i = 0; i < 8; ++i) s += v[i];
  const float m = wsum(s) * (1.0f / 512.0f);
  float sq = 0.f;
#pragma unroll
  for (int i = 0; i < 8; ++i) { float d = v[i] - m; sq = fmaf(d, d, sq); }
  const float rs = rsqrtf(wsum(sq) * (1.0f / 512.0f) + 1e-5f);
  float4 g0 = ((const float4*)g)[lane], g1 = ((const float4*)g)[64 + lane];
  float4 b0 = ((const float4*)b)[lane], b1 = ((const float4*)b)[64 + lane];
  float r[8];
  r[0] = (v[0] - m) * rs * g0.x + b0.x; r[1] = (v[1] - m) * rs * g0.y + b0.y;
  r[2] = (v[2] - m) * rs * g0.z + b0.z; r[3] = (v[3] - m) * rs * g0.w + b0.w;
  r[4] = (v[4] - m) * rs * g1.x + b1.x; r[5] = (v[5] - m) * rs * g1.y + b1.y;
  r[6] = (v[6] - m) * rs * g1.z + b1.z; r[7] = (v[7] - m) * rs * g1.w + b1.w;
  if (outf) {
    float4* op = (float4*)(outf + (size_t)row * DD);
    op[lane] = make_float4(r[0], r[1], r[2], r[3]);
    op[64 + lane] = make_float4(r[4], r[5], r[6], r[7]);
  }
  ushort4 q0, q1;
  q0.x = f2b(r[0]); q0.y = f2b(r[1]); q0.z = f2b(r[2]); q0.w = f2b(r[3]);
  q1.x = f2b(r[4]); q1.y = f2b(r[5]); q1.z = f2b(r[6]); q1.w = f2b(r[7]);
  ushort4* ob = (ushort4*)(outb + (size_t)row * DD);
  ob[lane] = q0; ob[64 + lane] = q1;
}

// h = LN(t + xin)*g + b + h   (in-place on h)
__global__ __launch_bounds__(256) void resid_ln(const float* __restrict__ t,
                                                const float* __restrict__ xin,
                                                float* __restrict__ h,
                                                const float* __restrict__ g,
                                                const float* __restrict__ b) {
  const int wave = threadIdx.x >> 6, lane = threadIdx.x & 63;
  const int row = blockIdx.x * 4 + wave;
  const float* tp = t + (size_t)row * DD;
  const float* xp = xin + (size_t)row * DD;
  float4 t0 = ((const float4*)tp)[lane], t1 = ((const float4*)tp)[64 + lane];
  float4 x0 = ((const float4*)xp)[lane], x1 = ((const float4*)xp)[64 + lane];
  float v[8] = {t0.x + x0.x, t0.y + x0.y, t0.z + x0.z, t0.w + x0.w,
                t1.x + x1.x, t1.y + x1.y, t1.z + x1.z, t1.w + x1.w};
  float s = 0.f;
#pragma unroll
  for (int i = 0; i < 8; ++i) s += v[i];
  const float m = wsum(s) * (1.0f / 512.0f);
  float sq = 0.f;
#pragma unroll
  for (int i = 0; i < 8; ++i) { float d = v[i] - m; sq = fmaf(d, d, sq); }
  const float rs = rsqrtf(wsum(sq) * (1.0f / 512.0f) + 1e-5f);
  float4 g0 = ((const float4*)g)[lane], g1 = ((const float4*)g)[64 + lane];
  float4 b0 = ((const float4*)b)[lane], b1 = ((const float4*)b)[64 + lane];
  float4* hp = (float4*)(h + (size_t)row * DD);
  float4 h0 = hp[lane], h1 = hp[64 + lane];
  h0.x += (v[0] - m) * rs * g0.x + b0.x; h0.y += (v[1] - m) * rs * g0.y + b0.y;
  h0.z += (v[2] - m) * rs * g0.z + b0.z; h0.w += (v[3] - m) * rs * g0.w + b0.w;
  h1.x += (v[4] - m) * rs * g1.x + b1.x; h1.y += (v[5] - m) * rs * g1.y + b1.y;
  h1.z += (v[6] - m) * rs * g1.z + b1.z; h1.w += (v[7] - m) * rs * g1.w + b1.w;
  hp[lane] = h0; hp[64 + lane] = h1;
}

// ---------------- generic bf16 MFMA GEMM: C = A[M,K] @ Bt[N,K]^T ----------------
// EPI 0: f32 C0.  EPI 1: QKV split (q,k bf16 row-major; v -> vt[bh][d][t] bf16).
// EPI 2: bias+gelu -> bf16 C0.  EPI 3: bias + C0(f32) += .
template<int BM, int BN, int WM, int WN, int EPI>
__global__ __launch_bounds__(256) void mgemm(const unsigned short* __restrict__ A,
                                             const unsigned short* __restrict__ Bt,
                                             void* __restrict__ C0, void* __restrict__ C1,
                                             void* __restrict__ C2,
                                             const float* __restrict__ bias,
                                             int M, int N, int K) {
  constexpr int NW = (BM / WM) * (BN / WN);
  constexpr int FM = WM / 16, FN = WN / 16;
  __shared__ char smem[(BM + BN) * 128];
  char* sA = smem; char* sB = smem + BM * 128;
  const int tid = threadIdx.x, lane = tid & 63, wid = tid >> 6;
  const int row0 = blockIdx.y * BM, col0 = blockIdx.x * BN;
  const int wrow = (wid / (BN / WN)) * WM, wcol = (wid % (BN / WN)) * WN;
  f32x4 acc[FM][FN] = {};
  const char* Ag = (const char*)(A + (size_t)row0 * K);
  const char* Bg = (const char*)(Bt + (size_t)col0 * K);
  for (int k0 = 0; k0 < K; k0 += 64) {
    __syncthreads();
    stage_rows(sA, Ag + (size_t)k0 * 2, (size_t)K * 2, BM / 8, wid, NW, lane);
    stage_rows(sB, Bg + (size_t)k0 * 2, (size_t)K * 2, BN / 8, wid, NW, lane);
    __syncthreads();
#pragma unroll
    for (int kk = 0; kk < 2; ++kk) {
      bf16x8 af[FM], bfr[FN];
#pragma unroll
      for (int mi = 0; mi < FM; ++mi)
        af[mi] = frag_ld(sA, wrow + mi * 16 + (lane & 15), kk * 4 + (lane >> 4));
#pragma unroll
      for (int ni = 0; ni < FN; ++ni)
        bfr[ni] = frag_ld(sB, wcol + ni * 16 + (lane & 15), kk * 4 + (lane >> 4));
#pragma unroll
      for (int mi = 0; mi < FM; ++mi)
#pragma unroll
        for (int ni = 0; ni < FN; ++ni)
          acc[mi][ni] = __builtin_amdgcn_mfma_f32_16x16x32_bf16(af[mi], bfr[ni], acc[mi][ni], 0, 0, 0);
    }
  }
#pragma unroll
  for (int mi = 0; mi < FM; ++mi)
#pragma unroll
    for (int ni = 0; ni < FN; ++ni) {
      const int colb = col0 + wcol + ni * 16;
      const int col = colb + (lane & 15);
      const int rowb = row0 + wrow + mi * 16 + (lane >> 4) * 4;
      if (EPI == 1 && (colb >> 9) == 2) {      // V segment -> vt[bh][d][t], pack 4 tokens
        const int cc = col - 1024, hh = cc >> 6, d = cc & 63, b = rowb >> 9, t = rowb & 511;
        ushort4 pk;
        pk.x = f2b(acc[mi][ni][0]); pk.y = f2b(acc[mi][ni][1]);
        pk.z = f2b(acc[mi][ni][2]); pk.w = f2b(acc[mi][ni][3]);
        *(ushort4*)((unsigned short*)C2 + (((size_t)(b * 8 + hh) * 64 + d) << 9) + t) = pk;
      } else {
#pragma unroll
        for (int r = 0; r < 4; ++r) {
          const int row = rowb + r;
          const float v = acc[mi][ni][r];
          if (EPI == 0) {
            ((float*)C0)[(size_t)row * N + col] = v;
          } else if (EPI == 1) {
            if (colb < 512) ((unsigned short*)C0)[(size_t)row * 512 + col] = f2b(v);
            else            ((unsigned short*)C1)[(size_t)row * 512 + (col - 512)] = f2b(v);
          } else if (EPI == 2) {
            ((unsigned short*)C0)[(size_t)row * N + col] = f2b(gelu_f(v + bias[col]));
          } else {
            ((float*)C0)[(size_t)row * N + col] += v + bias[col];
          }
        }
      }
    }
}

// ---------------- scores = (Q K^T)/8 + key-pad mask, MFMA, 128x128 tile per (b,h) ------
__global__ __launch_bounds__(256) void qk_mfma(const unsigned short* __restrict__ q,
                                               const unsigned short* __restrict__ k,
                                               const int* __restrict__ pad,
                                               float* __restrict__ sc) {
  const int bh = blockIdx.z, b = bh >> 3, hh = bh & 7;
  const int i0 = blockIdx.y * 128, j0 = blockIdx.x * 128;
  __shared__ char smem[32768];
  char* sQ = smem; char* sK = smem + 16384;
  const int tid = threadIdx.x, lane = tid & 63, wid = tid >> 6;
  const int wrow = (wid >> 1) * 64, wcol = (wid & 1) * 64;
  const char* qg = (const char*)(q + ((size_t)(b * TC + i0)) * DD + hh * HD);
  const char* kg = (const char*)(k + ((size_t)(b * TC + j0)) * DD + hh * HD);
  stage_rows(sQ, qg, 1024, 16, wid, 4, lane);
  stage_rows(sK, kg, 1024, 16, wid, 4, lane);
  __syncthreads();
  f32x4 acc[4][4] = {};
#pragma unroll
  for (int kk = 0; kk < 2; ++kk) {
    bf16x8 af[4], bfr[4];
#pragma unroll
    for (int mi = 0; mi < 4; ++mi)
      af[mi] = frag_ld(sQ, wrow + mi * 16 + (lane & 15), kk * 4 + (lane >> 4));
#pragma unroll
    for (int ni = 0; ni < 4; ++ni)
      bfr[ni] = frag_ld(sK, wcol + ni * 16 + (lane & 15), kk * 4 + (lane >> 4));
#pragma unroll
    for (int mi = 0; mi < 4; ++mi)
#pragma unroll
      for (int ni = 0; ni < 4; ++ni)
        acc[mi][ni] = __builtin_amdgcn_mfma_f32_16x16x32_bf16(af[mi], bfr[ni], acc[mi][ni], 0, 0, 0);
  }
#pragma unroll
  for (int ni = 0; ni < 4; ++ni) {
    const int col = j0 + wcol + ni * 16 + (lane & 15);
    const int msk = pad[b * TC + col];
#pragma unroll
    for (int mi = 0; mi < 4; ++mi)
#pragma unroll
      for (int r = 0; r < 4; ++r) {
        const int row = i0 + wrow + mi * 16 + (lane >> 4) * 4 + r;
        sc[((size_t)bh * TC + row) * TC + col] = msk ? NEGV : acc[mi][ni][r] * 0.125f;
      }
  }
}

// ---------------- entmax15: 16 bisect + closed-form tau*, write bf16 probs in place ----
__global__ __launch_bounds__(256) void entmax_k(char* __restrict__ scb) {
  const int wave = threadIdx.x >> 6, lane = threadIdx.x & 63;
  const size_t row = (size_t)blockIdx.x * 4 + wave;
  float* p = (float*)(scb + row * 2048);
  float4 a = ((const float4*)p)[lane];
  float4 c = ((const float4*)p)[64 + lane];
  float v[8] = {a.x, a.y, a.z, a.w, c.x, c.y, c.z, c.w};
  float mx = -3.4e38f;
#pragma unroll
  for (int i = 0; i < 8; ++i) { v[i] *= 0.5f; mx = fmaxf(mx, v[i]); }
  mx = wmaxr(mx);
#pragma unroll
  for (int i = 0; i < 8; ++i) v[i] -= mx;
  float lo = -1.0f, hi = 0.0f;
  for (int it = 0; it < 16; ++it) {
    const float mid = 0.5f * (lo + hi);
    float s = 0.f;
#pragma unroll
    for (int i = 0; i < 8; ++i) { float d = fmaxf(v[i] - mid, 0.f); s = fmaf(d, d, s); }
    s = wsum(s);
    if (s >= 1.0f) lo = mid; else hi = mid;
  }
  const float tm = 0.5f * (lo + hi);
  float c1 = 0.f, s1 = 0.f, s2 = 0.f;
#pragma unroll
  for (int i = 0; i < 8; ++i) {
    const float msk = (v[i] > tm) ? 1.0f : 0.0f;
    c1 += msk; s1 += msk * v[i]; s2 = fmaf(msk * v[i], v[i], s2);
  }
  c1 = wsum(c1); s1 = wsum(s1); s2 = wsum(s2);
  const float disc = fmaxf(s1 * s1 - c1 * s2 + c1, 0.f);
  const float tau = (s1 - sqrtf(disc)) / c1;
  float pv[8], s = 0.f;
#pragma unroll
  for (int i = 0; i < 8; ++i) { float d = fmaxf(v[i] - tau, 0.f); pv[i] = d * d; s += pv[i]; }
  s = wsum(s);
  const float inv = 1.0f / s;
  ushort4 o0, o1;
  o0.x = f2b(pv[0] * inv); o0.y = f2b(pv[1] * inv); o0.z = f2b(pv[2] * inv); o0.w = f2b(pv[3] * inv);
  o1.x = f2b(pv[4] * inv); o1.y = f2b(pv[5] * inv); o1.z = f2b(pv[6] * inv); o1.w = f2b(pv[7] * inv);
  ((ushort4*)((char*)p))[lane] = o0;
  ((ushort4*)((char*)p + 512))[lane] = o1;
}

// ---------------- o = P @ V via MFMA; P bf16 rows (stride 2048B), V from vt[bh][d][t] --
__global__ __launch_bounds__(256) void av_mfma(const char* __restrict__ probs,
                                               const unsigned short* __restrict__ vt,
                                               unsigned short* __restrict__ attnout) {
  const int bh = blockIdx.y, b = bh >> 3, hh = bh & 7;
  const int i0 = blockIdx.x * 128;
  __shared__ char smem[128 * 128 + 64 * 128];
  char* sP = smem; char* sV = smem + 16384;
  const int tid = threadIdx.x, lane = tid & 63, wid = tid >> 6;
  const int wrow = (wid >> 1) * 64, wcol = (wid & 1) * 32;
  f32x4 acc[4][2] = {};
  const char* pg = probs + ((size_t)(bh * TC + i0)) * 2048;
  const char* vg = (const char*)(vt + ((size_t)bh * 64) * 512);
  for (int k0 = 0; k0 < TC; k0 += 64) {
    __syncthreads();
    stage_rows(sP, pg + (size_t)k0 * 2, 2048, 16, wid, 4, lane);
    stage_rows(sV, vg + (size_t)k0 * 2, 1024, 8, wid, 4, lane);
    __syncthreads();
#pragma unroll
    for (int kk = 0; kk < 2; ++kk) {
      bf16x8 af[4], bfr[2];
#pragma unroll
      for (int mi = 0; mi < 4; ++mi)
        af[mi] = frag_ld(sP, wrow + mi * 16 + (lane & 15), kk * 4 + (lane >> 4));
#pragma unroll
      for (int ni = 0; ni < 2; ++ni)
        bfr[ni] = frag_ld(sV, wcol + ni * 16 + (lane & 15), kk * 4 + (lane >> 4));
#pragma unroll
      for (int mi = 0; mi < 4; ++mi)
#pragma unroll
        for (int ni = 0; ni < 2; ++ni)
          acc[mi][ni] = __builtin_amdgcn_mfma_f32_16x16x32_bf16(af[mi], bfr[ni], acc[mi][ni], 0, 0, 0);
    }
  }
#pragma unroll
  for (int mi = 0; mi < 4; ++mi)
#pragma unroll
    for (int ni = 0; ni < 2; ++ni)
#pragma unroll
      for (int r = 0; r < 4; ++r) {
        const int row = i0 + wrow + mi * 16 + (lane >> 4) * 4 + r;
        const int d = wcol + ni * 16 + (lane & 15);
        attnout[((size_t)(b * TC + row)) * DD + hh * HD + d] = f2b(acc[mi][ni][r]);
      }
}

// ---------------- head ----------------
__global__ void head_k(const float* __restrict__ h, const float* __restrict__ w1,
                       const float* __restrict__ b1, const float* __restrict__ w2,
                       const float* __restrict__ b2, float* __restrict__ out) {
  __shared__ float z[BB][HEADH];
  const int tid = threadIdx.x;
  const int b = tid >> 5, j = tid & 31;
  const float* hr = h + (size_t)(b * TC) * DD;
  float s = 0.f;
  for (int kk = 0; kk < DD; ++kk) s = fmaf(hr[kk], w1[kk * HEADH + j], s);
  z[b][j] = fmaxf(s + b1[j], 0.f);
  __syncthreads();
  if (tid < BB) {
    float acc = b2[0];
#pragma unroll
    for (int q2 = 0; q2 < HEADH; ++q2) acc = fmaf(z[tid][q2], w2[q2], acc);
    out[tid] = acc;
  }
}

// ---------------- workspace layout ----------------
// f32: h 8M | xin 8M | t 8M | sc 64M ; u16: xinbf 4M | q 4M | k 4M | vt 4M | attn 4M | mid 2M
// u16 weights: qkvT 6M | woT 2M | f1T 1M | f2T 1M ; pad 16K  => 125,845,504 B
#define WS_NEED 125845504ull
static __device__ __align__(256) unsigned char g_fallback_ws[WS_NEED];

extern "C" void kernel_launch(void* const* d_in, const int* in_sizes, int n_in,
                              void* d_out, int out_size, void* d_ws, size_t ws_size,
                              hipStream_t stream) {
  const int*   x     = (const int*)d_in[0];
  const float* etab  = (const float*)d_in[1];
  const float* ptab  = (const float*)d_in[2];
  const float* cls   = (const float*)d_in[3];
  const float* Wq    = (const float*)d_in[4];
  const float* Wk    = (const float*)d_in[5];
  const float* Wv    = (const float*)d_in[6];
  const float* Wo    = (const float*)d_in[7];
  const float* an_g  = (const float*)d_in[8];
  const float* an_b  = (const float*)d_in[9];
  const float* ln1_g = (const float*)d_in[10];
  const float* ln1_b = (const float*)d_in[11];
  const float* ln2_g = (const float*)d_in[12];
  const float* ln2_b = (const float*)d_in[13];
  const float* f1_w  = (const float*)d_in[14];
  const float* f1_b  = (const float*)d_in[15];
  const float* f2_w  = (const float*)d_in[16];
  const float* f2_b  = (const float*)d_in[17];
  const float* h1_w  = (const float*)d_in[18];
  const float* h1_b  = (const float*)d_in[19];
  const float* h2_w  = (const float*)d_in[20];
  const float* h2_b  = (const float*)d_in[21];
  float* out = (float*)d_out;

  void* wsbase = d_ws;
  if (ws_size < WS_NEED) hipGetSymbolAddress(&wsbase, HIP_SYMBOL(g_fallback_ws));
  char* base = (char*)wsbase;
  const size_t MB = 1048576;
  float* h_    = (float*)(base);
  float* xin_  = (float*)(base + 8 * MB);
  float* t_    = (float*)(base + 16 * MB);
  char*  sc_   = base + 24 * MB;                       // f32 scores / bf16 probs in place
  unsigned short* xinb_ = (unsigned short*)(base + 88 * MB);
  unsigned short* q_    = (unsigned short*)(base + 92 * MB);
  unsigned short* k_    = (unsigned short*)(base + 96 * MB);
  unsigned short* vt_   = (unsigned short*)(base + 100 * MB);
  unsigned short* at_   = (unsigned short*)(base + 104 * MB);
  unsigned short* mid_  = (unsigned short*)(base + 108 * MB);
  unsigned short* qkvT_ = (unsigned short*)(base + 110 * MB);
  unsigned short* woT_  = (unsigned short*)(base + 116 * MB);
  unsigned short* f1T_  = (unsigned short*)(base + 118 * MB);
  unsigned short* f2T_  = (unsigned short*)(base + 119 * MB);
  int* pad_ = (int*)(base + 120 * MB);

  wprep<<<dim3(16, 16, 24), 256, 0, stream>>>(Wq, Wk, Wv, Wo, f1_w, f2_w, qkvT_, woT_, f1T_, f2T_);
  embed_k<<<NTOK, 64, 0, stream>>>(x, etab, ptab, cls, h_, pad_);

  for (int l = 0; l < LL; ++l) {
    ln_rows<<<NTOK / 4, 256, 0, stream>>>(h_, xin_, xinb_, ln1_g + l * DD, ln1_b + l * DD);
    mgemm<128, 128, 64, 64, 1><<<dim3(12, 32), 256, 0, stream>>>(
        xinb_, qkvT_ + (size_t)l * 1536 * 512, q_, k_, vt_, nullptr, NTOK, 1536, 512);
    qk_mfma<<<dim3(4, 4, 64), 256, 0, stream>>>(q_, k_, pad_, (float*)sc_);
    entmax_k<<<(BB * HH * TC) / 4, 256, 0, stream>>>(sc_);
    av_mfma<<<dim3(4, 64), 256, 0, stream>>>(sc_, vt_, at_);
    mgemm<128, 128, 64, 64, 0><<<dim3(4, 32), 256, 0, stream>>>(
        at_, woT_ + (size_t)l * 512 * 512, t_, nullptr, nullptr, nullptr, NTOK, 512, 512);
    resid_ln<<<NTOK / 4, 256, 0, stream>>>(t_, xin_, h_, an_g + l * DD, an_b + l * DD);
    ln_rows<<<NTOK / 4, 256, 0, stream>>>(h_, nullptr, xinb_, ln2_g + l * DD, ln2_b + l * DD);
    mgemm<64, 64, 32, 32, 2><<<dim3(4, 64), 256, 0, stream>>>(
        xinb_, f1T_ + (size_t)l * 256 * 512, mid_, nullptr, nullptr, f1_b + l * FF, NTOK, 256, 512);
    mgemm<64, 128, 32, 64, 3><<<dim3(4, 64), 256, 0, stream>>>(
        mid_, f2T_ + (size_t)l * 512 * 256, h_, nullptr, nullptr, f2_b + l * DD, NTOK, 512, 256);
  }

  head_k<<<1, 256, 0, stream>>>(h_, h1_w, h1_b, h2_w, h2_b, out);
}